// Round 5
// baseline (580.108 us; speedup 1.0000x reference)
//
#include <hip/hip_runtime.h>
#include <cstdint>
#include <cstddef>

// GCN: N=512, B=64, F=O=128, E=3, 2 layers. fp32 in memory, bf16 MFMA compute.
//
// SINGLE PERSISTENT KERNEL k_gcn: 512 blocks x 256 thr, 72KB LDS -> exactly
// 2 blocks/CU on 256 CUs = all blocks co-resident by construction. Phases
// separated by a device-scope grid barrier (agent acquire/release atomics ->
// L2 writeback/invalidate across XCDs):
//   P0 prep    : blocks 0..7 transpose weights -> wt bf16 [layer][4][o][f]
//   P1 support1: p -> (n-tile, b); Xs staged once, g=0..3 phases; convert
//                slice (adj fp32 -> adjb bf16, NT reads) interleaved per-g
//   P2 agg1    : p -> (b, m-tile); 3-deep LDS pipeline, counted vmcnt(12)
//   P3 support2: same as P1, no convert, x = layer-1 out
//   P4 agg2    : in-place on out
// Rationale: 3 structural rounds all landed ~400us while compulsory HBM is
// ~38us -> need the fused single dispatch in top-5 to see counters at all.

typedef __bf16 bf16x8 __attribute__((ext_vector_type(8)));
typedef float f32x4 __attribute__((ext_vector_type(4)));
typedef unsigned short u16x8 __attribute__((ext_vector_type(8)));

#define MFMA16(a, b, c) __builtin_amdgcn_mfma_f32_16x16x32_bf16((a), (b), (c), 0, 0, 0)
#define NBLK 512

__device__ __forceinline__ unsigned short f2bf(float f) {  // RNE
  union { float f; unsigned int i; } v;
  v.f = f;
  return (unsigned short)((v.i + 0x7FFFu + ((v.i >> 16) & 1u)) >> 16);
}

// async global->LDS, 16B per lane; lds dest = wave-uniform base + lane*16
__device__ __forceinline__ void gl_lds16(const void* g, void* l) {
  __builtin_amdgcn_global_load_lds(
      (__attribute__((address_space(1))) void*)(g),
      (__attribute__((address_space(3))) void*)(l), 16, 0, 0);
}

// Device-scope grid barrier. bar[0]=arrive count, bar[1]=generation.
// Thread 0: release(fetch_add) publishes this block's stores (L2 wb);
// spin RELAXED (no inv storm), then one ACQUIRE load (L2 inv) on exit.
// __syncthreads on both sides orders all other threads' memory ops.
__device__ __forceinline__ void gridbar(unsigned* bar) {
  __syncthreads();
  if (threadIdx.x == 0) {
    unsigned g = __hip_atomic_load(&bar[1], __ATOMIC_RELAXED, __HIP_MEMORY_SCOPE_AGENT);
    unsigned arrived =
        __hip_atomic_fetch_add(&bar[0], 1u, __ATOMIC_ACQ_REL, __HIP_MEMORY_SCOPE_AGENT) + 1u;
    if (arrived == (unsigned)NBLK) {
      __hip_atomic_store(&bar[0], 0u, __ATOMIC_RELAXED, __HIP_MEMORY_SCOPE_AGENT);
      __hip_atomic_store(&bar[1], g + 1u, __ATOMIC_RELEASE, __HIP_MEMORY_SCOPE_AGENT);
    } else {
      while (__hip_atomic_load(&bar[1], __ATOMIC_RELAXED, __HIP_MEMORY_SCOPE_AGENT) == g)
        __builtin_amdgcn_s_sleep(16);
      (void)__hip_atomic_load(&bar[1], __ATOMIC_ACQUIRE, __HIP_MEMORY_SCOPE_AGENT);
    }
  }
  __syncthreads();
}

// ---------------------------------------------------------------------------
// prep: block p<8 transposes one 128x128 weight fp32 -> bf16 [o][f].
// ---------------------------------------------------------------------------
__device__ void prep_phase(int p, int tid,
    const float* __restrict__ W1, const float* __restrict__ Wh1,
    const float* __restrict__ W2, const float* __restrict__ Wh2,
    unsigned short* __restrict__ wt, unsigned short* T /* 128*136 */) {
  const int layer = p >> 2, g = p & 3;
  const float* src = (g < 3) ? ((layer ? W2 : W1) + g * 16384)
                             : (layer ? Wh2 : Wh1);
  unsigned short* dst = wt + layer * 65536 + g * 16384;
#pragma unroll
  for (int i = 0; i < 16; ++i) {
    int c = i * 256 + tid, f = c >> 5, pp = (c & 31) * 4;
    float4 v = *(const float4*)(src + f * 128 + pp);
    T[(pp + 0) * 136 + f] = f2bf(v.x);
    T[(pp + 1) * 136 + f] = f2bf(v.y);
    T[(pp + 2) * 136 + f] = f2bf(v.z);
    T[(pp + 3) * 136 + f] = f2bf(v.w);
  }
  __syncthreads();
#pragma unroll
  for (int i = 0; i < 8; ++i) {
    int c = i * 256 + tid, o = c >> 4, pp = (c & 15) * 8;
    *(uint4*)(dst + o * 128 + pp) = *(const uint4*)(&T[o * 136 + pp]);
  }
}

// ---------------------------------------------------------------------------
// support: p -> n0=(p&7)*64, b=p>>3. Xs staged once; 4 g-phases (Ws restage).
// g<3 : D[o,n] = W[g]^T @ X^T -> sup bf16 (+bias)     (M=o 128, N=n 64)
// g==3: D[n,o] = X @ Wh       -> tg fp32 sigmoid      (M=n 64, O=o 128)
// If adjf != null: after each g, one convert slice (12 it x 2KB/thread-grp)
// adj fp32 -> adjb bf16, NT reads; overlaps next g's staging drain.
// ---------------------------------------------------------------------------
__device__ void support_phase(int p, int tid,
    const float* __restrict__ xin, const unsigned short* __restrict__ wtl,
    const float* __restrict__ bias, const float* __restrict__ bh,
    unsigned short* __restrict__ sup, float* __restrict__ tg,
    const float* __restrict__ adjf, unsigned short* __restrict__ adjb,
    unsigned short* Xs /*64x136*/, unsigned short* Ws /*128x136*/) {
  const int lane = tid & 63, wv = tid >> 6;
  const int l15 = lane & 15, q = lane >> 4;
  const int n0 = (p & 7) * 64, b = p >> 3;

  // stage Xs: 64 n-rows x 128 f (fp32 -> bf16), once for all 4 g-phases
#pragma unroll
  for (int is = 0; is < 8; ++is) {
    int flat = is * 256 + tid;  // 0..2047
    int row = flat >> 5, c4 = (flat & 31) * 4;
    float4 v = *(const float4*)(xin + (size_t)(n0 + row) * 8192 + b * 128 + c4);
    ushort4 u = { f2bf(v.x), f2bf(v.y), f2bf(v.z), f2bf(v.w) };
    *(ushort4*)(&Xs[row * 136 + c4]) = u;
  }

  for (int g = 0; g < 4; ++g) {
    __syncthreads();  // Ws overwrite vs previous g's reads (fences Xs at g=0)
#pragma unroll
    for (int is = 0; is < 8; ++is) {
      int flat = is * 256 + tid;
      int row = flat >> 4, c8 = (flat & 15) * 8;
      *(uint4*)(&Ws[row * 136 + c8]) =
          *(const uint4*)(wtl + g * 16384 + row * 128 + c8);
    }
    __syncthreads();

    if (g < 3) {
      f32x4 acc[4][2];
#pragma unroll
      for (int i = 0; i < 4; ++i)
#pragma unroll
        for (int j = 0; j < 2; ++j) acc[i][j] = (f32x4){0.f, 0.f, 0.f, 0.f};
#pragma unroll
      for (int kt = 0; kt < 4; ++kt) {
        int kf = kt * 32 + q * 8;
        bf16x8 a[4], bb[2];
#pragma unroll
        for (int mt = 0; mt < 4; ++mt)
          a[mt] = *(const bf16x8*)(&Ws[((wv >> 1) * 64 + mt * 16 + l15) * 136 + kf]);
#pragma unroll
        for (int nt = 0; nt < 2; ++nt)
          bb[nt] = *(const bf16x8*)(&Xs[((wv & 1) * 32 + nt * 16 + l15) * 136 + kf]);
#pragma unroll
        for (int mt = 0; mt < 4; ++mt)
#pragma unroll
          for (int nt = 0; nt < 2; ++nt)
            acc[mt][nt] = MFMA16(a[mt], bb[nt], acc[mt][nt]);
      }
      const size_t sb = (size_t)(g * 64 + b) * 65536;
#pragma unroll
      for (int mt = 0; mt < 4; ++mt) {
#pragma unroll
        for (int nt = 0; nt < 2; ++nt) {
          int nn = n0 + (wv & 1) * 32 + nt * 16 + l15;
#pragma unroll
          for (int r = 0; r < 4; ++r) {
            int o = (wv >> 1) * 64 + mt * 16 + q * 4 + r;
            float v = acc[mt][nt][r] + bias[g * 128 + o];
            sup[sb + (size_t)o * 512 + nn] = f2bf(v);
          }
        }
      }
    } else {
      f32x4 acc[2][4];
#pragma unroll
      for (int i = 0; i < 2; ++i)
#pragma unroll
        for (int j = 0; j < 4; ++j) acc[i][j] = (f32x4){0.f, 0.f, 0.f, 0.f};
#pragma unroll
      for (int kt = 0; kt < 4; ++kt) {
        int kf = kt * 32 + q * 8;
        bf16x8 a[2], bb[4];
#pragma unroll
        for (int mt = 0; mt < 2; ++mt)
          a[mt] = *(const bf16x8*)(&Xs[((wv >> 1) * 32 + mt * 16 + l15) * 136 + kf]);
#pragma unroll
        for (int nt = 0; nt < 4; ++nt)
          bb[nt] = *(const bf16x8*)(&Ws[((wv & 1) * 64 + nt * 16 + l15) * 136 + kf]);
#pragma unroll
        for (int mt = 0; mt < 2; ++mt)
#pragma unroll
          for (int nt = 0; nt < 4; ++nt)
            acc[mt][nt] = MFMA16(a[mt], bb[nt], acc[mt][nt]);
      }
#pragma unroll
      for (int mt = 0; mt < 2; ++mt) {
#pragma unroll
        for (int nt = 0; nt < 4; ++nt) {
          int o = (wv & 1) * 64 + nt * 16 + l15;
#pragma unroll
          for (int r = 0; r < 4; ++r) {
            int nn = n0 + (wv >> 1) * 32 + mt * 16 + q * 4 + r;
            float v = acc[mt][nt][r] + bh[o];
            tg[((size_t)nn * 64 + b) * 128 + o] = 1.f / (1.f + __expf(-v));
          }
        }
      }
    }

    if (adjf) {  // convert slice g: 3072 x8-chunks per (p,g), coalesced
      const long long base = ((long long)p * 4 + g) * 3072 + tid;
#pragma unroll 4
      for (int it = 0; it < 12; ++it) {
        long long i = base + (long long)it * 256;
        const f32x4* s4 = (const f32x4*)(adjf + i * 8);
        f32x4 v0 = __builtin_nontemporal_load(s4);      // adj fp32 dead after
        f32x4 v1 = __builtin_nontemporal_load(s4 + 1);
        u16x8 u = { f2bf(v0[0]), f2bf(v0[1]), f2bf(v0[2]), f2bf(v0[3]),
                    f2bf(v1[0]), f2bf(v1[1]), f2bf(v1[2]), f2bf(v1[3]) };
        *(u16x8*)(adjb + i * 8) = u;                    // cached: L3-hot for agg
      }
    }
  }
}

// ---------------------------------------------------------------------------
// agg: p -> b=p&63 (fast: same-b m-tiles share XCD), m0=(p>>6)*64.
// Block tile 64m x 128o, K=3e*512n in 24 chunks of 64. 3-deep LDS pipeline
// (As 3x8KB + Bs 3x16KB), XOR-swizzled 16B chunks, counted vmcnt(12),
// raw s_barrier, setprio around MFMA.
// ---------------------------------------------------------------------------
__device__ void agg_phase(int p, int tid,
    const unsigned short* __restrict__ adjb, const unsigned short* __restrict__ sup,
    const float* __restrict__ tg, const float* __restrict__ x,
    float* __restrict__ dst,
    unsigned short* As /*3*4096*/, unsigned short* Bs /*3*8192*/) {
  const int lane = tid & 63, wv = tid >> 6;
  const int l15 = lane & 15, q = lane >> 4;
  const int wm = wv >> 1, wn = wv & 1;
  const int b = p & 63, m0 = (p >> 6) * 64;
  const int srow = tid >> 3, sc = tid & 7;  // staging: row-in-32, 16B chunk

  f32x4 acc[2][4];
#pragma unroll
  for (int i = 0; i < 2; ++i)
#pragma unroll
    for (int j = 0; j < 4; ++j) acc[i][j] = (f32x4){0.f, 0.f, 0.f, 0.f};

  auto stage = [&](int ch, int buf) {
    const int e = ch >> 3, kt = ch & 7;
    const size_t arow0 = (size_t)(e * 64 + b) * 512 + m0;
    const size_t sbase = (size_t)(e * 64 + b) * 65536;
#pragma unroll
    for (int is = 0; is < 2; ++is) {
      int row = is * 32 + srow;
      int gc = sc ^ (row & 7);
      gl_lds16(adjb + (arow0 + row) * 512 + kt * 64 + gc * 8,
               &As[buf * 4096 + is * 2048 + wv * 512]);
    }
#pragma unroll
    for (int is = 0; is < 4; ++is) {
      int row = is * 32 + srow;
      int gc = sc ^ (row & 7);
      gl_lds16(sup + sbase + (size_t)row * 512 + kt * 64 + gc * 8,
               &Bs[buf * 8192 + is * 2048 + wv * 512]);
    }
  };

  stage(0, 0);  // prologue: chunks 0,1 in flight (12 loads)
  stage(1, 1);
  for (int ch = 0; ch < 24; ++ch) {
    const int buf = ch % 3;
    if (ch < 22) {
      stage(ch + 2, (ch + 2) % 3);  // 18 outstanding
      asm volatile("s_waitcnt vmcnt(12)" ::: "memory");  // chunk ch landed
    } else if (ch == 22) {
      asm volatile("s_waitcnt vmcnt(6)" ::: "memory");
    } else {
      asm volatile("s_waitcnt vmcnt(0)" ::: "memory");
    }
    __builtin_amdgcn_s_barrier();       // chunk-ch data visible in LDS
    asm volatile("" ::: "memory");
    __builtin_amdgcn_s_setprio(1);
#pragma unroll
    for (int kh = 0; kh < 2; ++kh) {
      bf16x8 af[2], bfr[4];
#pragma unroll
      for (int mt = 0; mt < 2; ++mt) {
        int r = wm * 32 + mt * 16 + l15;
        int pp = (kh * 4 + q) ^ (r & 7);
        af[mt] = *(const bf16x8*)(&As[buf * 4096 + r * 64 + pp * 8]);
      }
#pragma unroll
      for (int ot = 0; ot < 4; ++ot) {
        int r = wn * 64 + ot * 16 + l15;
        int pp = (kh * 4 + q) ^ (r & 7);
        bfr[ot] = *(const bf16x8*)(&Bs[buf * 8192 + r * 64 + pp * 8]);
      }
#pragma unroll
      for (int mt = 0; mt < 2; ++mt)
#pragma unroll
        for (int ot = 0; ot < 4; ++ot)
          acc[mt][ot] = MFMA16(af[mt], bfr[ot], acc[mt][ot]);
    }
    __builtin_amdgcn_s_setprio(0);
    asm volatile("" ::: "memory");
    __builtin_amdgcn_s_barrier();       // reads of buf done before restage
  }

  // Epilogue: relu + highway. C row=m (q*4+r), col=o (l15).
#pragma unroll
  for (int mt = 0; mt < 2; ++mt) {
#pragma unroll
    for (int ot = 0; ot < 4; ++ot) {
#pragma unroll
      for (int r = 0; r < 4; ++r) {
        int m = m0 + wm * 32 + mt * 16 + q * 4 + r;
        int o = wn * 64 + ot * 16 + l15;
        size_t ridx = (size_t)(m * 64 + b) * 128 + o;
        float agg = acc[mt][ot][r];
        agg = agg > 0.f ? agg : 0.f;
        float tv = tg[ridx];
        float xv = x[ridx];
        dst[ridx] = fmaf(agg, tv, xv * (1.f - tv));
      }
    }
  }
}

// ---------------------------------------------------------------------------
__global__ __launch_bounds__(256, 2) void k_gcn(
    const float* __restrict__ x, const float* __restrict__ adjf,
    const float* __restrict__ W1, const float* __restrict__ b1,
    const float* __restrict__ Wh1, const float* __restrict__ bh1,
    const float* __restrict__ W2, const float* __restrict__ b2,
    const float* __restrict__ Wh2, const float* __restrict__ bh2,
    unsigned short* __restrict__ adjb, unsigned short* __restrict__ sup,
    float* __restrict__ tg, unsigned short* __restrict__ wt,
    unsigned* __restrict__ bar, float* __restrict__ out) {
  __shared__ __align__(16) unsigned char SMEM[73728];  // 72KB -> 2 blocks/CU
  const int tid = threadIdx.x, p = blockIdx.x;

  unsigned short* Xs = (unsigned short*)SMEM;             // 64*136 shorts
  unsigned short* Ws = (unsigned short*)(SMEM + 17408);   // 128*136 shorts
  unsigned short* As = (unsigned short*)SMEM;             // 3*4096 shorts
  unsigned short* Bs = (unsigned short*)(SMEM + 24576);   // 3*8192 shorts

  // P0: weight prep (blocks 0..7)
  if (p < 8)
    prep_phase(p, tid, W1, Wh1, W2, Wh2, wt, (unsigned short*)SMEM);
  gridbar(bar);

  // P1: support layer 1 + adj convert (interleaved)
  support_phase(p, tid, x, wt, b1, bh1, sup, tg, adjf, adjb, Xs, Ws);
  gridbar(bar);

  // P2: agg layer 1 -> out
  agg_phase(p, tid, adjb, sup, tg, x, out, As, Bs);
  gridbar(bar);

  // P3: support layer 2 (x = layer-1 out)
  support_phase(p, tid, out, wt + 65536, b2, bh2, sup, tg, nullptr, nullptr, Xs, Ws);
  gridbar(bar);

  // P4: agg layer 2 (in-place on out)
  agg_phase(p, tid, adjb, sup, tg, out, out, As, Bs);
}

// ---------------------------------------------------------------------------
extern "C" void kernel_launch(void* const* d_in, const int* in_sizes, int n_in,
                              void* d_out, int out_size, void* d_ws, size_t ws_size,
                              hipStream_t stream) {
  const float* x   = (const float*)d_in[0];
  const float* adj = (const float*)d_in[1];
  const float* W1  = (const float*)d_in[2];
  const float* b1  = (const float*)d_in[3];
  const float* Wh1 = (const float*)d_in[4];
  const float* bh1 = (const float*)d_in[5];
  const float* W2  = (const float*)d_in[6];
  const float* b2  = (const float*)d_in[7];
  const float* Wh2 = (const float*)d_in[8];
  const float* bh2 = (const float*)d_in[9];
  float* out = (float*)d_out;

  char* ws = (char*)d_ws;
  unsigned short* adjb = (unsigned short*)ws;                // 100,663,296 B
  unsigned short* sup  = (unsigned short*)(ws + 100663296);  //  25,165,824 B
  float*          tg   = (float*)(ws + 125829120);           //  16,777,216 B
  unsigned short* wt   = (unsigned short*)(ws + 142606336);  //     262,144 B
  unsigned*       bar  = (unsigned*)(ws + 142868480);        //         128 B

  // barrier state must start zeroed (workspace is poisoned between runs)
  hipMemsetAsync(bar, 0, 128, stream);

  k_gcn<<<dim3(NBLK), dim3(256), 0, stream>>>(
      x, adj, W1, b1, Wh1, bh1, W2, b2, Wh2, bh2,
      adjb, sup, tg, wt, bar, out);
}